// Round 2
// baseline (119.882 us; speedup 1.0000x reference)
//
#include <hip/hip_runtime.h>

#define D_DIM 512

__device__ __forceinline__ float flog2(float x) {
    return __builtin_amdgcn_logf(x);   // v_log_f32 (= log2); inputs >= ~4e-6, no denormal wrapper
}

// ============ per-row sums: E[row] = sum_d x*log2(x). One wave/row, 4 rows/block ============
__global__ __launch_bounds__(256)
void jsd_entropy_kernel(const float* __restrict__ a,
                        const float* __restrict__ b,
                        float* __restrict__ E, int N, int M) {
    const int wave = threadIdx.x >> 6;
    const int lane = threadIdx.x & 63;
    const int row = blockIdx.x * 4 + wave;
    if (row >= N + M) return;
    const float* src = (row < N) ? (a + (size_t)row * D_DIM)
                                 : (b + (size_t)(row - N) * D_DIM);
    const float4* s4 = (const float4*)src;
    float4 v0 = s4[lane];
    float4 v1 = s4[lane + 64];
    float s = 0.f;
    s = fmaf(v0.x, flog2(v0.x), s);
    s = fmaf(v0.y, flog2(v0.y), s);
    s = fmaf(v0.z, flog2(v0.z), s);
    s = fmaf(v0.w, flog2(v0.w), s);
    s = fmaf(v1.x, flog2(v1.x), s);
    s = fmaf(v1.y, flog2(v1.y), s);
    s = fmaf(v1.z, flog2(v1.z), s);
    s = fmaf(v1.w, flog2(v1.w), s);
#pragma unroll
    for (int off = 32; off > 0; off >>= 1) s += __shfl_down(s, off, 64);
    if (lane == 0) E[row] = s;
}

// ============ main: out[i,j] = 1 + 0.5*(Ea[i]+Eb[j]) - 0.5*sum_d t*log2(t), t=a+b ============
// 32x32 tile, 256 threads (16x16), 2x2 per thread. Grid 32x32 = 1024 blocks
// -> 4 independent blocks/CU (16 waves/CU, 4/SIMD): enough independent waves to
// fill the ~33% VALU issue-idle seen in rounds 0/1.
constexpr int TR = 32;           // A-rows per block
constexpr int TC = 32;           // B-cols per block
constexpr int DK = 64;           // d per chunk
constexpr int NCH = D_DIM / DK;  // 8

// Stage a 32-row x DK f32 tile into LDS via global_load_lds dwordx4.
// LDS dest linear (HW requirement); swizzle LDS[r][chunk s] = global[r][chunk s ^ ((r>>1)&15)]
// applied by pre-swizzling the per-lane GLOBAL source address.
// (row>>1) swizzle => A-reads 4 distinct bank groups, B-reads all-16-distinct chunks.
__device__ __forceinline__ void stage32(const float* __restrict__ g,
                                        float* lbuf, int w, int l) {
#pragma unroll
    for (int k = 0; k < 2; ++k) {
        const int r0 = w * 8 + k * 4;          // wave w owns rows 8w..8w+7
        const int r  = r0 + (l >> 4);
        const int c  = (l & 15) ^ ((r >> 1) & 15);
        const float* gp = g + (size_t)r * D_DIM + 4 * c;
        __builtin_amdgcn_global_load_lds(
            (const __attribute__((address_space(1))) void*)gp,
            (__attribute__((address_space(3))) void*)(lbuf + r0 * DK),
            16, 0, 0);
    }
}

__global__ __launch_bounds__(256)
void jsd_main_kernel(const float* __restrict__ a, const float* __restrict__ b,
                     const float* __restrict__ Ea, const float* __restrict__ Eb,
                     float* __restrict__ out, int N, int M) {
    __shared__ __align__(16) float As[2][TR][DK];   // 16 KB
    __shared__ __align__(16) float Bs[2][TC][DK];   // 16 KB

    const int tid = threadIdx.x;
    const int tx = tid & 15;       // -> cols tx*2 + {0,1}
    const int ty = tid >> 4;       // -> rows ty*2 + {0,1}
    const int w  = tid >> 6;
    const int l  = tid & 63;
    const int rowBase = blockIdx.y * TR;
    const int colBase = blockIdx.x * TC;

    const float* aT = a + (size_t)rowBase * D_DIM;
    const float* bT = b + (size_t)colBase * D_DIM;

    float acc[2][2] = {};

    stage32(aT, &As[0][0][0], w, l);
    stage32(bT, &Bs[0][0][0], w, l);

#pragma unroll 1
    for (int ck = 0; ck < NCH; ++ck) {
        const int cur = ck & 1;
        asm volatile("s_waitcnt vmcnt(0)" ::: "memory");  // my chunk's loads landed
        __syncthreads();                                   // everyone's landed; prev reads done
        if (ck + 1 < NCH) {   // issue next chunk's loads; they fly under this chunk's compute
            stage32(aT + (ck + 1) * DK, &As[cur ^ 1][0][0], w, l);
            stage32(bT + (ck + 1) * DK, &Bs[cur ^ 1][0][0], w, l);
        }
        __builtin_amdgcn_sched_barrier(0);  // keep load-issue ahead of compute

#pragma unroll 8
        for (int q0 = 0; q0 < 16; ++q0) {
            // read swizzle matches stage side: slot = q0 ^ ((row>>1)&15); row>>1 = ty (A), tx (B)
            const int ca = ((q0 ^ ty) & 15) << 2;
            const int cb = ((q0 ^ tx) & 15) << 2;
            float4 av[2], bv[2];
            av[0] = *(const float4*)&As[cur][ty * 2 + 0][ca];
            av[1] = *(const float4*)&As[cur][ty * 2 + 1][ca];
            bv[0] = *(const float4*)&Bs[cur][tx * 2 + 0][cb];
            bv[1] = *(const float4*)&Bs[cur][tx * 2 + 1][cb];
#pragma unroll
            for (int rr = 0; rr < 2; ++rr)
#pragma unroll
                for (int cc = 0; cc < 2; ++cc) {
                    float t0 = av[rr].x + bv[cc].x;
                    float t1 = av[rr].y + bv[cc].y;
                    float t2 = av[rr].z + bv[cc].z;
                    float t3 = av[rr].w + bv[cc].w;
                    float s = acc[rr][cc];
                    s = fmaf(t0, flog2(t0), s);
                    s = fmaf(t1, flog2(t1), s);
                    s = fmaf(t2, flog2(t2), s);
                    s = fmaf(t3, flog2(t3), s);
                    acc[rr][cc] = s;
                }
        }
    }

    // epilogue: direct float2 stores (no atomics, no memset)
    const float ea0 = Ea[rowBase + ty * 2 + 0];
    const float ea1 = Ea[rowBase + ty * 2 + 1];
    const float2 ebv = *(const float2*)(Eb + colBase + tx * 2);
    float2 v0, v1;
    v0.x = fmaf(-0.5f, acc[0][0], 1.0f + 0.5f * (ea0 + ebv.x));
    v0.y = fmaf(-0.5f, acc[0][1], 1.0f + 0.5f * (ea0 + ebv.y));
    v1.x = fmaf(-0.5f, acc[1][0], 1.0f + 0.5f * (ea1 + ebv.x));
    v1.y = fmaf(-0.5f, acc[1][1], 1.0f + 0.5f * (ea1 + ebv.y));
    *(float2*)(out + (size_t)(rowBase + ty * 2 + 0) * M + colBase + tx * 2) = v0;
    *(float2*)(out + (size_t)(rowBase + ty * 2 + 1) * M + colBase + tx * 2) = v1;
}

extern "C" void kernel_launch(void* const* d_in, const int* in_sizes, int n_in,
                              void* d_out, int out_size, void* d_ws, size_t ws_size,
                              hipStream_t stream) {
    const float* a = (const float*)d_in[0];
    const float* b = (const float*)d_in[1];
    const int N = in_sizes[0] / D_DIM;   // 1024
    const int M = in_sizes[1] / D_DIM;   // 1024
    float* E = (float*)d_ws;             // Ea[0..N), Eb[N..N+M)

    jsd_entropy_kernel<<<(N + M + 3) / 4, 256, 0, stream>>>(a, b, E, N, M);

    dim3 grid(M / TC, N / TR);           // 32 x 32 = 1024 blocks -> 4 blocks/CU
    jsd_main_kernel<<<grid, 256, 0, stream>>>(a, b, E, E + N, (float*)d_out, N, M);
}

// Round 3
// 112.493 us; speedup vs baseline: 1.0657x; 1.0657x over previous
//
#include <hip/hip_runtime.h>

#define D_DIM 512

__device__ __forceinline__ float flog2(float x) {
    return __builtin_amdgcn_logf(x);   // v_log_f32 (= log2); inputs >= ~4e-6, no denormal wrapper
}

// ============ per-row sums: E[row] = sum_d x*log2(x). One wave/row, 4 rows/block ============
__global__ __launch_bounds__(256)
void jsd_entropy_kernel(const float* __restrict__ a,
                        const float* __restrict__ b,
                        float* __restrict__ E, int N, int M) {
    const int wave = threadIdx.x >> 6;
    const int lane = threadIdx.x & 63;
    const int row = blockIdx.x * 4 + wave;
    if (row >= N + M) return;
    const float* src = (row < N) ? (a + (size_t)row * D_DIM)
                                 : (b + (size_t)(row - N) * D_DIM);
    const float4* s4 = (const float4*)src;
    float4 v0 = s4[lane];
    float4 v1 = s4[lane + 64];
    float s = 0.f;
    s = fmaf(v0.x, flog2(v0.x), s);
    s = fmaf(v0.y, flog2(v0.y), s);
    s = fmaf(v0.z, flog2(v0.z), s);
    s = fmaf(v0.w, flog2(v0.w), s);
    s = fmaf(v1.x, flog2(v1.x), s);
    s = fmaf(v1.y, flog2(v1.y), s);
    s = fmaf(v1.z, flog2(v1.z), s);
    s = fmaf(v1.w, flog2(v1.w), s);
#pragma unroll
    for (int off = 32; off > 0; off >>= 1) s += __shfl_down(s, off, 64);
    if (lane == 0) E[row] = s;
}

// ============ main ============
// out[i,j] = 1 + 0.5*(Ea[i]+Eb[j]) - 0.5*sum_d t*log2(t), t = a_i[d]+b_j[d]
//
// One INDEPENDENT wave per (32x32 output tile, d-half). No __syncthreads in the
// main loop: each wave owns a private 16 KB LDS slice, double-buffered via
// global_load_lds, drained with its own vmcnt. 4x4 per-lane blocking ->
// 0.5 LDS-float per element-op (LDS pipe ~20 us/CU << 41 us VALU floor).
// Block = 4 waves = {2 col-tiles} x {2 d-halves}; the d-half pair merges via
// LDS once at the end (no atomics, no memset).
constexpr int DK  = 32;          // d per chunk (row = 128 B in LDS)
constexpr int NCH = 8;           // chunks per d-half (8*32 = 256)

// Stage 32 rows x 32 d into linear LDS [32][32] (wave-private).
// Swizzle: LDS[r][16B-slot s] = global[r][chunk s ^ ((r>>2)&7)], applied by
// pre-swizzling the per-lane GLOBAL source (LDS dest must stay linear).
__device__ __forceinline__ void stageW(const float* __restrict__ g, float* lbuf, int l) {
#pragma unroll
    for (int k = 0; k < 4; ++k) {
        const int r0 = 8 * k;
        const int r  = r0 + (l >> 3);
        const int c  = (l & 7) ^ ((r >> 2) & 7);
        const float* gp = g + (size_t)r * D_DIM + 4 * c;
        __builtin_amdgcn_global_load_lds(
            (const __attribute__((address_space(1))) void*)gp,
            (__attribute__((address_space(3))) void*)(lbuf + r0 * DK),
            16, 0, 0);
    }
}

__global__ __launch_bounds__(256)
void jsd_main_kernel(const float* __restrict__ a, const float* __restrict__ b,
                     const float* __restrict__ Ea, const float* __restrict__ Eb,
                     float* __restrict__ out, int N, int M) {
    __shared__ __align__(16) float lds[4][2][2][32][DK];   // [wave][buf][A/B][row][d] = 64 KB

    const int tid  = threadIdx.x;
    const int w    = tid >> 6;
    const int l    = tid & 63;
    const int lr   = l >> 3;         // lane row group: rows 4*lr..4*lr+3
    const int lc   = l & 7;          // lane col group: cols 4*lc..4*lc+3
    const int half = w & 1;          // d-half (0: d<256, 1: d>=256)
    const int ct   = w >> 1;         // col-tile within block
    const int rowBase = blockIdx.y * 32;
    const int colBase = blockIdx.x * 64 + ct * 32;

    const float* aT = a + (size_t)rowBase * D_DIM + half * 256;
    const float* bT = b + (size_t)colBase * D_DIM + half * 256;

    float* A0 = &lds[w][0][0][0][0];
    float* B0 = &lds[w][0][1][0][0];
    float* A1 = &lds[w][1][0][0][0];
    float* B1 = &lds[w][1][1][0][0];

    float acc[4][4] = {};

    stageW(aT, A0, l);
    stageW(bT, B0, l);

#pragma unroll 1
    for (int ck = 0; ck < NCH; ++ck) {
        asm volatile("s_waitcnt vmcnt(0)" ::: "memory");   // this wave's chunk landed
        float* Aw = (ck & 1) ? A1 : A0;
        float* Bw = (ck & 1) ? B1 : B0;
        if (ck + 1 < NCH) {            // prefetch next chunk; flies under this chunk's compute
            stageW(aT + (ck + 1) * DK, (ck & 1) ? A0 : A1, l);
            stageW(bT + (ck + 1) * DK, (ck & 1) ? B0 : B1, l);
        }
        __builtin_amdgcn_sched_barrier(0);   // keep load-issue ahead of compute

#pragma unroll
        for (int q = 0; q < 8; ++q) {
            const int sa = ((q ^ lr) & 7) << 2;   // read-side swizzle: (r>>2)&7 = lr
            const int sb = ((q ^ lc) & 7) << 2;   //                    (r>>2)&7 = lc
            float4 av[4], bv[4];
#pragma unroll
            for (int i = 0; i < 4; ++i) av[i] = *(const float4*)&Aw[(4 * lr + i) * DK + sa];
#pragma unroll
            for (int i = 0; i < 4; ++i) bv[i] = *(const float4*)&Bw[(4 * lc + i) * DK + sb];
#pragma unroll
            for (int rr = 0; rr < 4; ++rr)
#pragma unroll
                for (int cc = 0; cc < 4; ++cc) {
                    float s = acc[rr][cc];
                    float t0 = av[rr].x + bv[cc].x;
                    float t1 = av[rr].y + bv[cc].y;
                    float t2 = av[rr].z + bv[cc].z;
                    float t3 = av[rr].w + bv[cc].w;
                    s = fmaf(t0, flog2(t0), s);
                    s = fmaf(t1, flog2(t1), s);
                    s = fmaf(t2, flog2(t2), s);
                    s = fmaf(t3, flog2(t3), s);
                    acc[rr][cc] = s;
                }
        }
    }

    // -------- merge d-halves within the wave pair (one barrier, no atomics) --------
    float* marea = &lds[w][0][0][0][0];            // reuse own buf0 (2048 floats)
    if (half) {
#pragma unroll
        for (int i = 0; i < 16; ++i)
            marea[i * 65 + l] = acc[i >> 2][i & 3];   // stride 65: conflict-free
    }
    __syncthreads();
    if (!half) {
        const float* pm = &lds[w + 1][0][0][0][0];
        float ea[4];
#pragma unroll
        for (int rr = 0; rr < 4; ++rr) ea[rr] = Ea[rowBase + 4 * lr + rr];
        const float4 eb = *(const float4*)&Eb[colBase + 4 * lc];
#pragma unroll
        for (int rr = 0; rr < 4; ++rr) {
            float s0 = acc[rr][0] + pm[(rr * 4 + 0) * 65 + l];
            float s1 = acc[rr][1] + pm[(rr * 4 + 1) * 65 + l];
            float s2 = acc[rr][2] + pm[(rr * 4 + 2) * 65 + l];
            float s3 = acc[rr][3] + pm[(rr * 4 + 3) * 65 + l];
            const float base = 1.0f + 0.5f * ea[rr];
            float4 v;
            v.x = fmaf(-0.5f, s0, base + 0.5f * eb.x);
            v.y = fmaf(-0.5f, s1, base + 0.5f * eb.y);
            v.z = fmaf(-0.5f, s2, base + 0.5f * eb.z);
            v.w = fmaf(-0.5f, s3, base + 0.5f * eb.w);
            *(float4*)(out + (size_t)(rowBase + 4 * lr + rr) * M + colBase + 4 * lc) = v;
        }
    }
}

extern "C" void kernel_launch(void* const* d_in, const int* in_sizes, int n_in,
                              void* d_out, int out_size, void* d_ws, size_t ws_size,
                              hipStream_t stream) {
    const float* a = (const float*)d_in[0];
    const float* b = (const float*)d_in[1];
    const int N = in_sizes[0] / D_DIM;   // 1024
    const int M = in_sizes[1] / D_DIM;   // 1024
    float* E = (float*)d_ws;             // Ea[0..N), Eb[N..N+M)

    jsd_entropy_kernel<<<(N + M + 3) / 4, 256, 0, stream>>>(a, b, E, N, M);

    dim3 grid(M / 64, N / 32);           // 16 x 32 = 512 blocks -> 2 blocks/CU, 8 indep waves/CU
    jsd_main_kernel<<<grid, 256, 0, stream>>>(a, b, E, E + N, (float*)d_out, N, M);
}

// Round 4
// 108.288 us; speedup vs baseline: 1.1071x; 1.0388x over previous
//
#include <hip/hip_runtime.h>

#define D_DIM 512

typedef float f32x2 __attribute__((ext_vector_type(2)));

__device__ __forceinline__ float flog2(float x) {
    return __builtin_amdgcn_logf(x);   // v_log_f32 (= log2); inputs >= ~4e-6, no denormal wrapper
}

// ============ per-row sums: E[row] = sum_d x*log2(x). One wave/row, 4 rows/block ============
__global__ __launch_bounds__(256)
void jsd_entropy_kernel(const float* __restrict__ a,
                        const float* __restrict__ b,
                        float* __restrict__ E, int N, int M) {
    const int wave = threadIdx.x >> 6;
    const int lane = threadIdx.x & 63;
    const int row = blockIdx.x * 4 + wave;
    if (row >= N + M) return;
    const float* src = (row < N) ? (a + (size_t)row * D_DIM)
                                 : (b + (size_t)(row - N) * D_DIM);
    const float4* s4 = (const float4*)src;
    float4 v0 = s4[lane];
    float4 v1 = s4[lane + 64];
    float s = 0.f;
    s = fmaf(v0.x, flog2(v0.x), s);
    s = fmaf(v0.y, flog2(v0.y), s);
    s = fmaf(v0.z, flog2(v0.z), s);
    s = fmaf(v0.w, flog2(v0.w), s);
    s = fmaf(v1.x, flog2(v1.x), s);
    s = fmaf(v1.y, flog2(v1.y), s);
    s = fmaf(v1.z, flog2(v1.z), s);
    s = fmaf(v1.w, flog2(v1.w), s);
#pragma unroll
    for (int off = 32; off > 0; off >>= 1) s += __shfl_down(s, off, 64);
    if (lane == 0) E[row] = s;
}

// ============ main ============
// out[i,j] = 1 + 0.5*(Ea[i]+Eb[j]) - 0.5*sum_d t*log2(t), t = a_i[d]+b_j[d]
//
// Block = 256 thr = 4 waves = one 32x32 output tile x 4 INDEPENDENT d-quarters.
// No barrier in the main loop: each wave owns a private 8 KB LDS slice,
// double-buffered via global_load_lds, drained with its own vmcnt.
// 32 KB LDS/block + VGPR<=128 -> 4 blocks/CU = 4 independent waves/SIMD.
// Packed f32 (pk_add/pk_fma via float2) cuts the non-log VALU work in half:
// serial floor 41 -> 34 us. 4-way d-merge via LDS at the end (no atomics).
constexpr int DK  = 16;          // d per chunk (row = 64 B in LDS, 4 float4 slots)
constexpr int QD  = 128;         // d per wave (quarter)
constexpr int NCH = QD / DK;     // 8

// Stage 32 rows x 16 d into linear LDS [32][16] (wave-private).
// Swizzle: LDS[r][16B-slot s] = global[r][chunk s ^ ((r>>2)&3)], applied by
// pre-swizzling the per-lane GLOBAL source (LDS dest must stay linear).
__device__ __forceinline__ void stageW(const float* __restrict__ g, float* lbuf, int l) {
#pragma unroll
    for (int k = 0; k < 2; ++k) {
        const int r0 = 16 * k;
        const int r  = r0 + (l >> 2);
        const int c  = (l & 3) ^ ((r >> 2) & 3);
        const float* gp = g + (size_t)r * D_DIM + 4 * c;
        __builtin_amdgcn_global_load_lds(
            (const __attribute__((address_space(1))) void*)gp,
            (__attribute__((address_space(3))) void*)(lbuf + r0 * DK),
            16, 0, 0);
    }
}

__global__ __launch_bounds__(256, 4)
void jsd_main_kernel(const float* __restrict__ a, const float* __restrict__ b,
                     const float* __restrict__ Ea, const float* __restrict__ Eb,
                     float* __restrict__ out, int N, int M) {
    __shared__ __align__(16) float lds[4][2][2][32][DK];   // [wave][buf][A/B][row][d] = 32 KB

    const int tid = threadIdx.x;
    const int w   = tid >> 6;        // wave = d-quarter
    const int l   = tid & 63;
    const int lr  = l >> 3;          // lane row group: rows 4*lr..4*lr+3
    const int lc  = l & 7;           // lane col group: cols 4*lc..4*lc+3
    const int rowBase = blockIdx.y * 32;
    const int colBase = blockIdx.x * 32;

    const float* aT = a + (size_t)rowBase * D_DIM + w * QD;
    const float* bT = b + (size_t)colBase * D_DIM + w * QD;

    float* A0 = &lds[w][0][0][0][0];
    float* B0 = &lds[w][0][1][0][0];
    float* A1 = &lds[w][1][0][0][0];
    float* B1 = &lds[w][1][1][0][0];

    f32x2 acc2[4][4];
#pragma unroll
    for (int i = 0; i < 4; ++i)
#pragma unroll
        for (int j = 0; j < 4; ++j) acc2[i][j] = (f32x2){0.f, 0.f};

    stageW(aT, A0, l);
    stageW(bT, B0, l);

#pragma unroll 1
    for (int ck = 0; ck < NCH; ++ck) {
        asm volatile("s_waitcnt vmcnt(0)" ::: "memory");   // this wave's chunk landed
        float* Aw = (ck & 1) ? A1 : A0;
        float* Bw = (ck & 1) ? B1 : B0;
        if (ck + 1 < NCH) {            // prefetch next chunk; flies under this chunk's compute
            stageW(aT + (ck + 1) * DK, (ck & 1) ? A0 : A1, l);
            stageW(bT + (ck + 1) * DK, (ck & 1) ? B0 : B1, l);
        }
        __builtin_amdgcn_sched_barrier(0);   // keep load-issue ahead of compute

#pragma unroll
        for (int q = 0; q < 4; ++q) {
            const int sa = ((q ^ lr) & 3) << 2;   // read-side swizzle: (r>>2)&3 = lr&3
            const int sb = ((q ^ lc) & 3) << 2;   //                    (r>>2)&3 = lc&3
            float4 av[4], bv[4];
#pragma unroll
            for (int i = 0; i < 4; ++i) av[i] = *(const float4*)&Aw[(4 * lr + i) * DK + sa];
#pragma unroll
            for (int i = 0; i < 4; ++i) bv[i] = *(const float4*)&Bw[(4 * lc + i) * DK + sb];
#pragma unroll
            for (int rr = 0; rr < 4; ++rr) {
                const f32x2 a0 = {av[rr].x, av[rr].y};
                const f32x2 a1 = {av[rr].z, av[rr].w};
#pragma unroll
                for (int cc = 0; cc < 4; ++cc) {
                    f32x2 t0 = a0 + (f32x2){bv[cc].x, bv[cc].y};   // v_pk_add_f32
                    f32x2 t1 = a1 + (f32x2){bv[cc].z, bv[cc].w};
                    f32x2 l0 = {flog2(t0.x), flog2(t0.y)};
                    f32x2 l1 = {flog2(t1.x), flog2(t1.y)};
                    acc2[rr][cc] = __builtin_elementwise_fma(t0, l0, acc2[rr][cc]);  // v_pk_fma_f32
                    acc2[rr][cc] = __builtin_elementwise_fma(t1, l1, acc2[rr][cc]);
                }
            }
        }
    }

    // -------- 4-way d-merge via LDS (two barriers, no atomics) --------
    float accs[16];
#pragma unroll
    for (int i = 0; i < 16; ++i) accs[i] = acc2[i >> 2][i & 3].x + acc2[i >> 2][i & 3].y;

    __syncthreads();                       // everyone done reading their LDS slice
    float* base = &lds[0][0][0][0][0];     // 8192 floats scratch; need 4*16*65 = 4160
#pragma unroll
    for (int i = 0; i < 16; ++i)
        base[(w * 16 + i) * 65 + l] = accs[i];   // stride 65: conflict-free
    __syncthreads();

    // wave w combines + stores rows 4*lr + w
    const int rr = w;
    float s[4];
#pragma unroll
    for (int cc = 0; cc < 4; ++cc) {
        float v = base[(0 * 16 + rr * 4 + cc) * 65 + l];
        v += base[(1 * 16 + rr * 4 + cc) * 65 + l];
        v += base[(2 * 16 + rr * 4 + cc) * 65 + l];
        v += base[(3 * 16 + rr * 4 + cc) * 65 + l];
        s[cc] = v;
    }
    const int row = rowBase + 4 * lr + rr;
    const float eav = Ea[row];
    const float4 eb = *(const float4*)&Eb[colBase + 4 * lc];
    const float base_v = 1.0f + 0.5f * eav;
    float4 v;
    v.x = fmaf(-0.5f, s[0], base_v + 0.5f * eb.x);
    v.y = fmaf(-0.5f, s[1], base_v + 0.5f * eb.y);
    v.z = fmaf(-0.5f, s[2], base_v + 0.5f * eb.z);
    v.w = fmaf(-0.5f, s[3], base_v + 0.5f * eb.w);
    *(float4*)(out + (size_t)row * M + colBase + 4 * lc) = v;
}

extern "C" void kernel_launch(void* const* d_in, const int* in_sizes, int n_in,
                              void* d_out, int out_size, void* d_ws, size_t ws_size,
                              hipStream_t stream) {
    const float* a = (const float*)d_in[0];
    const float* b = (const float*)d_in[1];
    const int N = in_sizes[0] / D_DIM;   // 1024
    const int M = in_sizes[1] / D_DIM;   // 1024
    float* E = (float*)d_ws;             // Ea[0..N), Eb[N..N+M)

    jsd_entropy_kernel<<<(N + M + 3) / 4, 256, 0, stream>>>(a, b, E, N, M);

    dim3 grid(M / 32, N / 32);           // 32 x 32 = 1024 blocks -> 4 blocks/CU, 16 indep waves/CU
    jsd_main_kernel<<<grid, 256, 0, stream>>>(a, b, E, E + N, (float*)d_out, N, M);
}